// Round 7
// baseline (717.615 us; speedup 1.0000x reference)
//
#include <hip/hip_runtime.h>
#include <math.h>

#define HIDDEN 256
#define HEADS 4
#define HEAD_DIM 64
#define LAYERS 3
#define NUM_GRAPHS 64
#define NEG_SLOPE 0.2f

typedef short short8 __attribute__((ext_vector_type(8)));
typedef float floatx4 __attribute__((ext_vector_type(4)));

// ---------- helpers ----------
static __device__ __forceinline__ float elu_f(float x) {
    return x > 0.f ? x : expm1f(x);
}

static __device__ __forceinline__ float waveReduceSum(float v) {
#pragma unroll
    for (int off = 32; off > 0; off >>= 1) v += __shfl_xor(v, off, 64);
    return v;
}

// fp32 <-> bf16 (RNE)
static __device__ __forceinline__ ushort f2bf(float f) {
    unsigned u = __float_as_uint(f);
    unsigned r = (u + 0x7FFFu + ((u >> 16) & 1u)) >> 16;
    return (ushort)r;
}
static __device__ __forceinline__ float bf2f(ushort h) {
    return __uint_as_float(((unsigned)h) << 16);
}

// ---------- CSR build ----------
__global__ void hist_kernel(const int* __restrict__ dst, int* __restrict__ deg, int E) {
    int e = blockIdx.x * blockDim.x + threadIdx.x;
    if (e < E) atomicAdd(&deg[dst[e]], 1);
}

__global__ __launch_bounds__(256) void blocksum_kernel(const int* __restrict__ deg,
                                                       int* __restrict__ bsum, int N) {
    int i = blockIdx.x * 256 + threadIdx.x;
    int v = (i < N) ? deg[i] : 0;
    __shared__ int red[4];
    int s = v;
#pragma unroll
    for (int off = 32; off > 0; off >>= 1) s += __shfl_xor(s, off, 64);
    if ((threadIdx.x & 63) == 0) red[threadIdx.x >> 6] = s;
    __syncthreads();
    if (threadIdx.x == 0) bsum[blockIdx.x] = red[0] + red[1] + red[2] + red[3];
}

__global__ __launch_bounds__(256) void scan_bsums(int* __restrict__ bsum, int nblk) {
    __shared__ int sh[256];
    int t = threadIdx.x;
    int v = (t < nblk) ? bsum[t] : 0;
    sh[t] = v;
    __syncthreads();
#pragma unroll
    for (int off = 1; off < 256; off <<= 1) {
        int add = (t >= off) ? sh[t - off] : 0;
        __syncthreads();
        sh[t] += add;
        __syncthreads();
    }
    if (t < nblk) bsum[t] = sh[t] - v;   // exclusive
}

__global__ __launch_bounds__(256) void writeptr_kernel(const int* __restrict__ deg,
                                                       const int* __restrict__ bsum,
                                                       int* __restrict__ rowptr,
                                                       int* __restrict__ nxt,
                                                       int N, int E) {
    __shared__ int sh[256];
    int t = threadIdx.x;
    int i = blockIdx.x * 256 + t;
    int v = (i < N) ? deg[i] : 0;
    sh[t] = v;
    __syncthreads();
#pragma unroll
    for (int off = 1; off < 256; off <<= 1) {
        int add = (t >= off) ? sh[t - off] : 0;
        __syncthreads();
        sh[t] += add;
        __syncthreads();
    }
    if (i < N) {
        int r = bsum[blockIdx.x] + sh[t] - v;
        rowptr[i] = r;
        nxt[i] = r;
    }
    if (i == 0) rowptr[N] = E;
}

// scatter: ONE packed 16B record per edge in CSR slot order:
// emeta[slot] = { src(int), e0, e1, e2 }
__global__ void scatter_kernel(const int* __restrict__ src, const int* __restrict__ dst,
                               const float* __restrict__ ea,
                               int* __restrict__ nxt, uint4* __restrict__ emeta, int E) {
    int e = blockIdx.x * blockDim.x + threadIdx.x;
    if (e >= E) return;
    int d = dst[e];
    int slot = atomicAdd(&nxt[d], 1);
    uint4 mt;
    mt.x = (unsigned)src[e];
    mt.y = __float_as_uint(ea[(size_t)e * 3]);
    mt.z = __float_as_uint(ea[(size_t)e * 3 + 1]);
    mt.w = __float_as_uint(ea[(size_t)e * 3 + 2]);
    emeta[slot] = mt;
}

// ---------- tiny precompute: w_ea[l][h][k] = sum_d We[l,k,h*64+d] * a_e[l,h,d] ----------
__global__ void wea_kernel(const float* __restrict__ We, const float* __restrict__ a_e,
                           float* __restrict__ w_ea) {
    int t = threadIdx.x;
    if (t < LAYERS * HEADS * 3) {
        int l = t / 12, r = t % 12, h = r / 3, k = r % 3;
        float s = 0.f;
        for (int d = 0; d < HEAD_DIM; ++d)
            s += We[l * 3 * HIDDEN + k * HIDDEN + h * HEAD_DIM + d] *
                 a_e[l * HIDDEN + h * HEAD_DIM + d];
        w_ea[t] = s;
    }
}

// ---------- weight convert+transpose: Wt[l][n][k] = bf16(W_l[k][n]) ----------
__global__ void conv_w(const float* __restrict__ Wg, const float* __restrict__ Wo,
                       ushort* __restrict__ Wt) {
    int l = blockIdx.x;
    int n = blockIdx.y;
    int k = threadIdx.x;
    const float* W = (l < 3) ? (Wg + (size_t)l * HIDDEN * HIDDEN) : Wo;
    Wt[(size_t)l * HIDDEN * HIDDEN + (size_t)n * HIDDEN + k] =
        f2bf(W[(size_t)k * HIDDEN + n]);
}

// ---------- input projection + LayerNorm + ELU (bf16 output only) ----------
__global__ __launch_bounds__(256) void inproj_ln(const float* __restrict__ x,
                                                 const float* __restrict__ W,
                                                 const float* __restrict__ b,
                                                 const float* __restrict__ g,
                                                 const float* __restrict__ beta,
                                                 ushort* __restrict__ hb) {
    int n = blockIdx.x;
    int c = threadIdx.x;
    float acc = b[c];
#pragma unroll
    for (int k = 0; k < 8; ++k) acc += x[n * 8 + k] * W[k * HIDDEN + c];
    __shared__ float red[8];
    float s = waveReduceSum(acc);
    float s2 = waveReduceSum(acc * acc);
    int w = c >> 6;
    if ((c & 63) == 0) { red[w] = s; red[4 + w] = s2; }
    __syncthreads();
    float mu = (red[0] + red[1] + red[2] + red[3]) * (1.f / 256.f);
    float ms = (red[4] + red[5] + red[6] + red[7]) * (1.f / 256.f);
    float inv = rsqrtf(ms - mu * mu + 1e-5f);
    float y = elu_f((acc - mu) * inv * g[c] + beta[c]);
    hb[(size_t)n * HIDDEN + c] = f2bf(y);
}

// ---------- LayerNorm + ELU (final, fp32 input) ----------
__global__ __launch_bounds__(256) void ln_elu(const float* __restrict__ t,
                                              const float* __restrict__ g,
                                              const float* __restrict__ beta,
                                              float* __restrict__ out) {
    int n = blockIdx.x;
    int c = threadIdx.x;
    float acc = t[(size_t)n * HIDDEN + c];
    __shared__ float red[8];
    float s = waveReduceSum(acc);
    float s2 = waveReduceSum(acc * acc);
    int w = c >> 6;
    if ((c & 63) == 0) { red[w] = s; red[4 + w] = s2; }
    __syncthreads();
    float mu = (red[0] + red[1] + red[2] + red[3]) * (1.f / 256.f);
    float ms = (red[4] + red[5] + red[6] + red[7]) * (1.f / 256.f);
    float inv = rsqrtf(ms - mu * mu + 1e-5f);
    float y = (acc - mu) * inv * g[c] + beta[c];
    out[(size_t)n * HIDDEN + c] = elu_f(y);
}

// ---------- bf16 MFMA GEMM (register double-buffered) + fused scores ----------
#define ASTR 40
__global__ __launch_bounds__(256) void gemm_mfma(const ushort* __restrict__ A,
                                                 const ushort* __restrict__ Bt,
                                                 const float* __restrict__ bias,
                                                 float* __restrict__ C32,
                                                 ushort* __restrict__ C16,
                                                 const float* __restrict__ a_s,
                                                 const float* __restrict__ a_d,
                                                 float* __restrict__ s_src,
                                                 float* __restrict__ s_dst,
                                                 int doScore) {
    const int K = 256;
    __shared__ ushort As[128 * ASTR];
    __shared__ ushort Bs[128 * ASTR];
    int m0 = blockIdx.x * 128;
    int n0 = blockIdx.y * 128;
    int t = threadIdx.x;
    int wave = t >> 6, lane = t & 63;
    int wr = wave >> 1, wc = wave & 1;
    int lrow = lane & 15;
    int quad = lane >> 4;
    floatx4 acc[4][4] = {};
    int r = t >> 2, q = t & 3;
    const ushort* Ar0 = A + (size_t)(m0 + r) * K + q * 8;
    const ushort* Ar1 = A + (size_t)(m0 + r + 64) * K + q * 8;
    const ushort* Br0 = Bt + (size_t)(n0 + r) * K + q * 8;
    const ushort* Br1 = Bt + (size_t)(n0 + r + 64) * K + q * 8;
    uint4 ra0 = *(const uint4*)(Ar0);
    uint4 ra1 = *(const uint4*)(Ar1);
    uint4 rb0 = *(const uint4*)(Br0);
    uint4 rb1 = *(const uint4*)(Br1);
    for (int k0 = 0; k0 < K; k0 += 32) {
        *(uint4*)&As[(r) * ASTR + q * 8] = ra0;
        *(uint4*)&As[(r + 64) * ASTR + q * 8] = ra1;
        *(uint4*)&Bs[(r) * ASTR + q * 8] = rb0;
        *(uint4*)&Bs[(r + 64) * ASTR + q * 8] = rb1;
        __syncthreads();
        if (k0 + 32 < K) {   // prefetch next tile while MFMA runs on this one
            ra0 = *(const uint4*)(Ar0 + k0 + 32);
            ra1 = *(const uint4*)(Ar1 + k0 + 32);
            rb0 = *(const uint4*)(Br0 + k0 + 32);
            rb1 = *(const uint4*)(Br1 + k0 + 32);
        }
        short8 af[4], bfr[4];
#pragma unroll
        for (int i = 0; i < 4; ++i)
            af[i] = *(const short8*)&As[(wr * 64 + i * 16 + lrow) * ASTR + quad * 8];
#pragma unroll
        for (int j = 0; j < 4; ++j)
            bfr[j] = *(const short8*)&Bs[(wc * 64 + j * 16 + lrow) * ASTR + quad * 8];
#pragma unroll
        for (int i = 0; i < 4; ++i)
#pragma unroll
            for (int j = 0; j < 4; ++j)
                acc[i][j] = __builtin_amdgcn_mfma_f32_16x16x32_bf16(af[i], bfr[j],
                                                                    acc[i][j], 0, 0, 0);
        __syncthreads();
    }
    int hh = (n0 + wc * 64) >> 6;
    int ncol[4];
    float bv4[4], asv[4], adv[4];
#pragma unroll
    for (int j = 0; j < 4; ++j) {
        int n = n0 + wc * 64 + j * 16 + lrow;
        ncol[j] = n;
        bv4[j] = bias[n];
        asv[j] = a_s[n];
        adv[j] = a_d[n];
    }
#pragma unroll
    for (int i = 0; i < 4; ++i) {
#pragma unroll
        for (int rg = 0; rg < 4; ++rg) {
            int mrow = m0 + wr * 64 + i * 16 + quad * 4 + rg;
            float ps = 0.f, pd = 0.f;
#pragma unroll
            for (int j = 0; j < 4; ++j) {
                float v = acc[i][j][rg] + bv4[j];
                if (C32) C32[(size_t)mrow * HIDDEN + ncol[j]] = v;
                if (C16) C16[(size_t)mrow * HIDDEN + ncol[j]] = f2bf(v);
                ps = fmaf(v, asv[j], ps);
                pd = fmaf(v, adv[j], pd);
            }
            if (doScore) {
#pragma unroll
                for (int off = 1; off < 16; off <<= 1) {
                    ps += __shfl_xor(ps, off, 64);
                    pd += __shfl_xor(pd, off, 64);
                }
                if (lrow == 0) {
                    s_src[mrow * 4 + hh] = ps;
                    s_dst[mrow * 4 + hh] = pd;
                }
            }
        }
    }
}

// ---------- wave-per-node aggregation, chunk-level flash softmax ----------
// 4 nodes/block. Lane l: head h=l>>4, chunk slot e4=l&15, channels c0=4l..4l+3.
// Full 16-edge chunks: all 16 gathers issued back-to-back (deep MLP) before the
// FMA chain; tail chunk uses the guarded loop. Residual stream is bf16.
__global__ __launch_bounds__(256) void aggregate(const int* __restrict__ rowptr,
                                                 const uint4* __restrict__ emeta,
                                                 const float* __restrict__ wea_l,
                                                 const float* __restrict__ s_src,
                                                 const float* __restrict__ s_dst,
                                                 const ushort* __restrict__ hpb,
                                                 const ushort* __restrict__ h_in_bf,
                                                 ushort* __restrict__ h_out_bf,
                                                 int N) {
    int wv = threadIdx.x >> 6;
    int n = blockIdx.x * 4 + wv;
    if (n >= N) return;
    int l = threadIdx.x & 63;
    int h = l >> 4;
    int e4 = l & 15;
    int c0 = l * 4;
    float w0 = wea_l[h * 3], w1 = wea_l[h * 3 + 1], w2 = wea_l[h * 3 + 2];
    float sdn = s_dst[n * 4 + h];
    int beg = rowptr[n];
    int cnt = rowptr[n + 1] - beg;
    float m = -3e38f, dsum = 0.f, a0 = 0.f, a1 = 0.f, a2 = 0.f, a3 = 0.f;
    int ch = 0;
    // ---- full chunks ----
    for (; ch + 16 <= cnt; ch += 16) {
        uint4 mt = emeta[beg + ch + e4];
        int s = (int)mt.x;
        float esc = __uint_as_float(mt.y) * w0 + __uint_as_float(mt.z) * w1 +
                    __uint_as_float(mt.w) * w2;
        float tv = sdn + s_src[s * 4 + h] + esc;
        float lg = tv > 0.f ? tv : NEG_SLOPE * tv;
        float cm = lg;
#pragma unroll
        for (int off = 1; off < 16; off <<= 1)
            cm = fmaxf(cm, __shfl_xor(cm, off, 64));
        float mn = fmaxf(m, cm);
        float scl = __expf(m - mn);
        m = mn;
        dsum *= scl; a0 *= scl; a1 *= scl; a2 *= scl; a3 *= scl;
        float ex = __expf(lg - mn);
        float exj[16];
        int sj[16];
#pragma unroll
        for (int j = 0; j < 16; ++j) {
            exj[j] = __shfl(ex, (h << 4) | j, 64);
            sj[j] = __shfl(s, j, 64);
        }
        uint2 v[16];
#pragma unroll
        for (int j = 0; j < 16; ++j)
            v[j] = *(const uint2*)(hpb + (size_t)sj[j] * HIDDEN + c0);
#pragma unroll
        for (int j = 0; j < 16; ++j) {
            dsum += exj[j];
            a0 = fmaf(__uint_as_float(v[j].x << 16), exj[j], a0);
            a1 = fmaf(__uint_as_float(v[j].x & 0xFFFF0000u), exj[j], a1);
            a2 = fmaf(__uint_as_float(v[j].y << 16), exj[j], a2);
            a3 = fmaf(__uint_as_float(v[j].y & 0xFFFF0000u), exj[j], a3);
        }
    }
    // ---- tail chunk ----
    if (ch < cnt) {
        int i = ch + e4;
        int s = 0;
        float lg = -3e38f;
        if (i < cnt) {
            uint4 mt = emeta[beg + i];
            s = (int)mt.x;
            float esc = __uint_as_float(mt.y) * w0 + __uint_as_float(mt.z) * w1 +
                        __uint_as_float(mt.w) * w2;
            float tv = sdn + s_src[s * 4 + h] + esc;
            lg = tv > 0.f ? tv : NEG_SLOPE * tv;
        }
        float cm = lg;
#pragma unroll
        for (int off = 1; off < 16; off <<= 1)
            cm = fmaxf(cm, __shfl_xor(cm, off, 64));
        float mn = fmaxf(m, cm);
        float scl = __expf(m - mn);
        m = mn;
        dsum *= scl; a0 *= scl; a1 *= scl; a2 *= scl; a3 *= scl;
        float ex = __expf(lg - mn);
        int lim = cnt - ch;
#pragma unroll 4
        for (int j = 0; j < lim; ++j) {
            float exj = __shfl(ex, (h << 4) | j, 64);
            int sj = __shfl(s, j, 64);
            uint2 v = *(const uint2*)(hpb + (size_t)sj * HIDDEN + c0);
            dsum += exj;
            a0 = fmaf(__uint_as_float(v.x << 16), exj, a0);
            a1 = fmaf(__uint_as_float(v.x & 0xFFFF0000u), exj, a1);
            a2 = fmaf(__uint_as_float(v.y << 16), exj, a2);
            a3 = fmaf(__uint_as_float(v.y & 0xFFFF0000u), exj, a3);
        }
    }
    float inv = 1.f / fmaxf(dsum, 1e-16f);
    ushort4 hib = *(const ushort4*)(h_in_bf + (size_t)n * HIDDEN + c0);
    float y0 = elu_f(fmaf(a0, inv, bf2f(hib.x)));
    float y1 = elu_f(fmaf(a1, inv, bf2f(hib.y)));
    float y2 = elu_f(fmaf(a2, inv, bf2f(hib.z)));
    float y3 = elu_f(fmaf(a3, inv, bf2f(hib.w)));
    ushort4 yb = {f2bf(y0), f2bf(y1), f2bf(y2), f2bf(y3)};
    *(ushort4*)(h_out_bf + (size_t)n * HIDDEN + c0) = yb;
}

// ---------- parallel pool ----------
__global__ __launch_bounds__(256) void pool_partial(const float* __restrict__ nemb,
                                                    const int* __restrict__ batch,
                                                    float* __restrict__ gout, int N) {
    int r0 = blockIdx.x * 128;
    int c = threadIdx.x;
    __shared__ int bsh[128];
    if (c < 128) {
        int r = r0 + c;
        bsh[c] = (r < N) ? batch[r] : -1;
    }
    __syncthreads();
    int rend = min(128, N - r0);
    float acc = 0.f;
    int cur = bsh[0];
    for (int i = 0; i < rend; ++i) {
        int g = bsh[i];
        if (g != cur) {
            atomicAdd(&gout[cur * HIDDEN + c], acc);
            acc = 0.f;
            cur = g;
        }
        acc += nemb[(size_t)(r0 + i) * HIDDEN + c];
    }
    if (cur >= 0) atomicAdd(&gout[cur * HIDDEN + c], acc);
}

__global__ void pool_div(float* __restrict__ gout, const int* __restrict__ batch, int N) {
    int g = blockIdx.x;
    int c = threadIdx.x;
    int lo = 0, hi = N;
    while (lo < hi) { int mid = (lo + hi) >> 1; if (batch[mid] < g) lo = mid + 1; else hi = mid; }
    int start = lo;
    lo = start; hi = N;
    while (lo < hi) { int mid = (lo + hi) >> 1; if (batch[mid] < g + 1) lo = mid + 1; else hi = mid; }
    float cnt = (float)(lo - start);
    gout[g * HIDDEN + c] /= fmaxf(cnt, 1.f);
}

extern "C" void kernel_launch(void* const* d_in, const int* in_sizes, int n_in,
                              void* d_out, int out_size, void* d_ws, size_t ws_size,
                              hipStream_t stream) {
    const float* x       = (const float*)d_in[0];
    const int*   ei      = (const int*)d_in[1];
    const float* ea      = (const float*)d_in[2];
    const int*   batch   = (const int*)d_in[3];
    const float* W_in    = (const float*)d_in[4];
    const float* b_in    = (const float*)d_in[5];
    const float* ln_in_g = (const float*)d_in[6];
    const float* ln_in_b = (const float*)d_in[7];
    const float* W_gat   = (const float*)d_in[8];
    const float* b_gat   = (const float*)d_in[9];
    const float* W_e     = (const float*)d_in[10];
    const float* a_src   = (const float*)d_in[11];
    const float* a_dst   = (const float*)d_in[12];
    const float* a_edge  = (const float*)d_in[13];
    const float* W_out   = (const float*)d_in[14];
    const float* b_out   = (const float*)d_in[15];
    const float* ln_out_g= (const float*)d_in[16];
    const float* ln_out_b= (const float*)d_in[17];

    int N = in_sizes[0] / 8;
    int E = in_sizes[1] / 2;
    int Mpad = (N + 127) & ~127;
    int nblk = (N + 255) / 256;     // <=256 assumed (N<=65536)
    const int* srcA = ei;
    const int* dstA = ei + E;

    char* w = (char*)d_ws;
    size_t off = 0;
    auto alloc = [&](size_t bytes) {
        void* p = w + off;
        off += (bytes + 255) & ~(size_t)255;
        return p;
    };
    ushort*   hAb    = (ushort*)alloc((size_t)Mpad * HIDDEN * 2);  // bf16 residual A
    ushort*   hBb    = (ushort*)alloc((size_t)Mpad * HIDDEN * 2);  // bf16 residual B
    ushort*   hpb    = (ushort*)alloc((size_t)Mpad * HIDDEN * 2);  // bf16 GEMM output
    float*    hp32   = (float*)alloc((size_t)Mpad * HIDDEN * 4);   // final proj fp32
    float*    sSrc   = (float*)alloc((size_t)Mpad * 4 * 4);
    float*    sDst   = (float*)alloc((size_t)Mpad * 4 * 4);
    int*      deg    = (int*)alloc((size_t)N * 4);
    int*      rowptr = (int*)alloc((size_t)(N + 1) * 4);
    int*      nxt    = (int*)alloc((size_t)N * 4);
    int*      bsum   = (int*)alloc(256 * 4);
    uint4*    emeta  = (uint4*)alloc((size_t)E * 16);
    float*    wea    = (float*)alloc(64 * 4);
    ushort*   Wt     = (ushort*)alloc((size_t)4 * HIDDEN * HIDDEN * 2);

    // --- CSR by dst (parallel 3-stage scan) + packed edge metadata + weights ---
    hipMemsetAsync(deg, 0, (size_t)N * 4, stream);
    hist_kernel<<<(E + 255) / 256, 256, 0, stream>>>(dstA, deg, E);
    blocksum_kernel<<<nblk, 256, 0, stream>>>(deg, bsum, N);
    scan_bsums<<<1, 256, 0, stream>>>(bsum, nblk);
    writeptr_kernel<<<nblk, 256, 0, stream>>>(deg, bsum, rowptr, nxt, N, E);
    wea_kernel<<<1, 64, 0, stream>>>(W_e, a_edge, wea);
    scatter_kernel<<<(E + 255) / 256, 256, 0, stream>>>(srcA, dstA, ea, nxt, emeta, E);
    conv_w<<<dim3(4, HIDDEN), 256, 0, stream>>>(W_gat, W_out, Wt);

    // --- input projection + LN + ELU (bf16 residual) ---
    inproj_ln<<<N, 256, 0, stream>>>(x, W_in, b_in, ln_in_g, ln_in_b, hAb);

    ushort* hcurb = hAb;
    ushort* hnextb = hBb;
    dim3 gg(Mpad / 128, HIDDEN / 128);
    for (int l = 0; l < LAYERS; ++l) {
        gemm_mfma<<<gg, 256, 0, stream>>>(hcurb, Wt + (size_t)l * HIDDEN * HIDDEN,
                                          b_gat + l * HIDDEN, nullptr, hpb,
                                          a_src + l * HIDDEN, a_dst + l * HIDDEN,
                                          sSrc, sDst, 1);
        aggregate<<<(N + 3) / 4, 256, 0, stream>>>(rowptr, emeta, wea + l * 12,
                                                   sSrc, sDst, hpb, hcurb, hnextb, N);
        ushort* tb = hcurb; hcurb = hnextb; hnextb = tb;
    }

    // --- output projection + LN + pool ---
    gemm_mfma<<<gg, 256, 0, stream>>>(hcurb, Wt + (size_t)3 * HIDDEN * HIDDEN,
                                      b_out, hp32, nullptr, a_src, a_dst, sSrc, sDst, 0);
    float* gout = (float*)d_out;
    float* nemb = gout + (size_t)NUM_GRAPHS * HIDDEN;
    ln_elu<<<N, 256, 0, stream>>>(hp32, ln_out_g, ln_out_b, nemb);
    hipMemsetAsync(gout, 0, (size_t)NUM_GRAPHS * HIDDEN * 4, stream);
    pool_partial<<<(N + 127) / 128, 256, 0, stream>>>(nemb, batch, gout, N);
    pool_div<<<NUM_GRAPHS, 256, 0, stream>>>(gout, batch, N);
}